// Round 13
// baseline (260.379 us; speedup 1.0000x reference)
//
#include <hip/hip_runtime.h>

#define IMGS 64
#define HH 512
#define WW 512
#define NPIX (HH * WW)          // 262144 pixels per image
#define STEPS 10
#define RSTRIP 16               // rows per wave strip
#define BLKS_PER_IMG 32         // 512 / 16
#define NBLK (IMGS * BLKS_PER_IMG)   // 2048 blocks, 128 threads each
#define WPI 64                  // partials per image per step (32 blk * 2 waves)

// ---------------------------------------------------------------------------
// kconv<FIRST,STORE>: one erosion step, register sliding-window stencil
// (unchanged from round 12; used for step 0, the stats-only A passes, and
// step 9). See comments there.
// ---------------------------------------------------------------------------
template <int FIRST, int STORE>
__global__ __launch_bounds__(128) void kconv(const float* __restrict__ xg,
                                             const float* __restrict__ yg,
                                             const float* __restrict__ src,
                                             float* __restrict__ dst,
                                             const float2* __restrict__ prevMM,
                                             float2* __restrict__ pmm,
                                             double* __restrict__ psum) {
    const int bid = blockIdx.x;
    const int swz = (bid & 7) * (NBLK / 8) + (bid >> 3);  // XCD-contiguous
    const int img = swz >> 5;
    const int blk = swz & 31;
    const int tid = threadIdx.x;
    const int w = tid >> 6;
    const int lane = tid & 63;
    const int vc = w * 64 + lane;
    const int ys = blk * RSTRIP;
    const size_t base = (size_t)img * NPIX;

    float scale = 1.0f, off = 0.0f;
    if (!FIRST) {
        float2 a = prevMM[img * WPI + lane];
        float tmn = a.x, tmx = a.y;
        #pragma unroll
        for (int o2 = 32; o2 > 0; o2 >>= 1) {
            tmn = fminf(tmn, __shfl_xor(tmn, o2));
            tmx = fmaxf(tmx, __shfl_xor(tmx, o2));
        }
        float ptp = tmx - tmn;
        if (ptp > 0.0f) { scale = 1.0f / ptp; off = tmn * scale; }
    }

    const float4* xv = (const float4*)(xg + base);
    const float4* yv = (const float4*)(yg + base);
    const float4* sv = (const float4*)(src + base);

    auto ld4 = [&](int r) -> float4 {
        if (FIRST) {
            float4 a = xv[r * 128 + vc];
            float4 b = yv[r * 128 + vc];
            float4 v;
            v.x = (a.x - b.x) * (a.x - b.x);
            v.y = (a.y - b.y) * (a.y - b.y);
            v.z = (a.z - b.z) * (a.z - b.z);
            v.w = (a.w - b.w) * (a.w - b.w);
            return v;
        } else {
            float4 v = sv[r * 128 + vc];
            v.x = fmaf(v.x, scale, -off);
            v.y = fmaf(v.y, scale, -off);
            v.z = fmaf(v.z, scale, -off);
            v.w = fmaf(v.w, scale, -off);
            return v;
        }
    };
    auto ld1 = [&](int r, int pcol) -> float {
        if (FIRST) {
            float d = xg[base + r * WW + pcol] - yg[base + r * WW + pcol];
            return d * d;
        } else {
            return fmaf(src[base + r * WW + pcol], scale, -off);
        }
    };

    const float4 z4 = make_float4(0.f, 0.f, 0.f, 0.f);
    float4 pm1 = (ys > 0) ? ld4(ys - 1) : z4;
    float4 p0 = ld4(ys);

    float tmin = __uint_as_float(0x7f800000u);
    float tmax = 0.0f;
    float tsum = 0.0f;
    float4* dv = (float4*)(dst + base);

    #pragma unroll
    for (int i = 0; i < RSTRIP; ++i) {
        const int y = ys + i;
        float4 p1 = (y + 1 < HH) ? ld4(y + 1) : z4;

        float lf = __shfl_up(p0.w, 1);
        float rt = __shfl_down(p0.x, 1);
        if (lane == 0)  lf = (vc > 0)   ? ld1(y, vc * 4 - 1) : 0.0f;
        if (lane == 63) rt = (vc < 127) ? ld1(y, vc * 4 + 4) : 0.0f;

        float4 e;
        e.x = 0.2f * (pm1.x + p1.x + lf   + p0.x + p0.y);
        e.y = 0.2f * (pm1.y + p1.y + p0.x + p0.y + p0.z);
        e.z = 0.2f * (pm1.z + p1.z + p0.y + p0.z + p0.w);
        e.w = 0.2f * (pm1.w + p1.w + p0.z + p0.w + rt);
        e.x = fmaxf(e.x - 0.5f, 0.0f);
        e.y = fmaxf(e.y - 0.5f, 0.0f);
        e.z = fmaxf(e.z - 0.5f, 0.0f);
        e.w = fmaxf(e.w - 0.5f, 0.0f);

        if (STORE) dv[y * 128 + vc] = e;

        tmin = fminf(tmin, fminf(fminf(e.x, e.y), fminf(e.z, e.w)));
        tmax = fmaxf(tmax, fmaxf(fmaxf(e.x, e.y), fmaxf(e.z, e.w)));
        tsum += (e.x + e.y) + (e.z + e.w);

        pm1 = p0;
        p0 = p1;
    }

    double dsum = (double)tsum;
    #pragma unroll
    for (int o2 = 32; o2 > 0; o2 >>= 1) {
        tmin = fminf(tmin, __shfl_down(tmin, o2));
        tmax = fmaxf(tmax, __shfl_down(tmax, o2));
        dsum += __shfl_down(dsum, o2);
    }

    if (lane == 0) {
        const int idx = img * WPI + blk * 2 + w;
        pmm[idx] = make_float2(tmin, tmax);
        psum[idx] = dsum;
    }
}

// ---------------------------------------------------------------------------
// kfuse: TWO erosion steps in one pass (stats/recompute split).
//   Reads f_{k-1} (norm by stats mmA = s_{k-1}), recomputes ero_k rows
//   ys-1..ys+16 in registers (bit-identical to the A pass), normalizes them
//   with stats mmB = s_k, applies the second 5-tap stencil -> ero_{k+1},
//   writes f_{k+1} and its stats. f_k is NEVER materialized.
//   Wave-edge ero_k pixels (cols P0-1, P0+256) are recomputed scalar-wise by
//   lanes 0/63 from cached loads. OOB of each normalized field is exact 0.
// ---------------------------------------------------------------------------
__global__ __launch_bounds__(128) void kfuse(const float* __restrict__ src,
                                             float* __restrict__ dst,
                                             const float2* __restrict__ mmA,
                                             const float2* __restrict__ mmB,
                                             float2* __restrict__ pmm,
                                             double* __restrict__ psum) {
    const int bid = blockIdx.x;
    const int swz = (bid & 7) * (NBLK / 8) + (bid >> 3);
    const int img = swz >> 5;
    const int blk = swz & 31;
    const int tid = threadIdx.x;
    const int w = tid >> 6;
    const int lane = tid & 63;
    const int vc = w * 64 + lane;
    const int ys = blk * RSTRIP;
    const size_t base = (size_t)img * NPIX;

    // butterfly-reduce both stat sets (64 partials each)
    float2 a1 = mmA[img * WPI + lane];
    float2 a2 = mmB[img * WPI + lane];
    float mn1 = a1.x, mx1 = a1.y, mn2 = a2.x, mx2 = a2.y;
    #pragma unroll
    for (int o2 = 32; o2 > 0; o2 >>= 1) {
        mn1 = fminf(mn1, __shfl_xor(mn1, o2));
        mx1 = fmaxf(mx1, __shfl_xor(mx1, o2));
        mn2 = fminf(mn2, __shfl_xor(mn2, o2));
        mx2 = fmaxf(mx2, __shfl_xor(mx2, o2));
    }
    float s1 = 1.0f, o1 = 0.0f;
    { float p = mx1 - mn1; if (p > 0.0f) { s1 = 1.0f / p; o1 = mn1 * s1; } }
    float s2 = 1.0f, o2v = 0.0f;
    { float p = mx2 - mn2; if (p > 0.0f) { s2 = 1.0f / p; o2v = mn2 * s2; } }

    const float4* sv = (const float4*)(src + base);
    auto ld4 = [&](int r) -> float4 {          // normalized f row r (in-bounds)
        float4 v = sv[r * 128 + vc];
        v.x = fmaf(v.x, s1, -o1);
        v.y = fmaf(v.y, s1, -o1);
        v.z = fmaf(v.z, s1, -o1);
        v.w = fmaf(v.w, s1, -o1);
        return v;
    };
    auto nat = [&](int r, int c) -> float {    // normalized f at (r,c), 0 OOB
        if (r < 0 || r >= HH || c < 0 || c >= WW) return 0.0f;
        return fmaf(src[base + r * WW + c], s1, -o1);
    };

    struct ERow { float4 m; float mL, mR; };   // normalized ero_k row + edges
    auto eroRow = [&](const float4& r0, const float4& r1, const float4& r2,
                      int yy) -> ERow {
        float lf = __shfl_up(r1.w, 1);
        float rt = __shfl_down(r1.x, 1);
        if (lane == 0)  lf = nat(yy, vc * 4 - 1);
        if (lane == 63) rt = nat(yy, vc * 4 + 4);
        float4 e;
        e.x = 0.2f * (r0.x + r2.x + lf   + r1.x + r1.y);
        e.y = 0.2f * (r0.y + r2.y + r1.x + r1.y + r1.z);
        e.z = 0.2f * (r0.z + r2.z + r1.y + r1.z + r1.w);
        e.w = 0.2f * (r0.w + r2.w + r1.z + r1.w + rt);
        e.x = fmaxf(e.x - 0.5f, 0.0f);
        e.y = fmaxf(e.y - 0.5f, 0.0f);
        e.z = fmaxf(e.z - 0.5f, 0.0f);
        e.w = fmaxf(e.w - 0.5f, 0.0f);
        ERow o;
        o.m.x = fmaf(e.x, s2, -o2v);
        o.m.y = fmaf(e.y, s2, -o2v);
        o.m.z = fmaf(e.z, s2, -o2v);
        o.m.w = fmaf(e.w, s2, -o2v);
        o.mL = 0.0f; o.mR = 0.0f;
        if (lane == 0) {
            const int pL = vc * 4 - 1;         // wave-left extra pixel
            if (pL >= 0) {
                float eL = 0.2f * (nat(yy - 1, pL) + nat(yy + 1, pL) +
                                   nat(yy, pL - 1) + nat(yy, pL) +
                                   nat(yy, pL + 1));
                eL = fmaxf(eL - 0.5f, 0.0f);
                o.mL = fmaf(eL, s2, -o2v);
            }
        }
        if (lane == 63) {
            const int pR = vc * 4 + 4;         // wave-right extra pixel
            if (pR < WW) {
                float eR = 0.2f * (nat(yy - 1, pR) + nat(yy + 1, pR) +
                                   nat(yy, pR - 1) + nat(yy, pR) +
                                   nat(yy, pR + 1));
                eR = fmaxf(eR - 0.5f, 0.0f);
                o.mR = fmaf(eR, s2, -o2v);
            }
        }
        return o;
    };

    const float4 z4 = make_float4(0.f, 0.f, 0.f, 0.f);
    ERow zer; zer.m = z4; zer.mL = 0.0f; zer.mR = 0.0f;

    // prologue: em1 = ero(ys-1), e0 = ero(ys); prime f-window (fa,fb)
    ERow em1, e0;
    float4 fa, fb;
    if (ys == 0) {
        em1 = zer;
        float4 f0 = ld4(0);
        float4 f1 = ld4(1);
        e0 = eroRow(z4, f0, f1, 0);
        fa = f0; fb = f1;
    } else {
        float4 fm2 = (ys >= 2) ? ld4(ys - 2) : z4;
        float4 fm1 = ld4(ys - 1);
        float4 f0 = ld4(ys);
        em1 = eroRow(fm2, fm1, f0, ys - 1);
        float4 f1 = ld4(ys + 1);               // ys+1 <= 497 < HH always
        e0 = eroRow(fm1, f0, f1, ys);
        fa = f0; fb = f1;
    }

    float tmin = __uint_as_float(0x7f800000u);
    float tmax = 0.0f;
    float tsum = 0.0f;
    float4* dv = (float4*)(dst + base);

    #pragma unroll
    for (int i = 0; i < RSTRIP; ++i) {
        const int y = ys + i;
        ERow ep1;
        if (y + 1 < HH) {
            float4 fc = (y + 2 < HH) ? ld4(y + 2) : z4;
            ep1 = eroRow(fa, fb, fc, y + 1);
            fa = fb; fb = fc;
        } else {
            ep1 = zer;
        }

        float lf = __shfl_up(e0.m.w, 1);
        float rt = __shfl_down(e0.m.x, 1);
        if (lane == 0)  lf = e0.mL;
        if (lane == 63) rt = e0.mR;

        float4 g;
        g.x = 0.2f * (em1.m.x + ep1.m.x + lf     + e0.m.x + e0.m.y);
        g.y = 0.2f * (em1.m.y + ep1.m.y + e0.m.x + e0.m.y + e0.m.z);
        g.z = 0.2f * (em1.m.z + ep1.m.z + e0.m.y + e0.m.z + e0.m.w);
        g.w = 0.2f * (em1.m.w + ep1.m.w + e0.m.z + e0.m.w + rt);
        g.x = fmaxf(g.x - 0.5f, 0.0f);
        g.y = fmaxf(g.y - 0.5f, 0.0f);
        g.z = fmaxf(g.z - 0.5f, 0.0f);
        g.w = fmaxf(g.w - 0.5f, 0.0f);

        dv[y * 128 + vc] = g;

        tmin = fminf(tmin, fminf(fminf(g.x, g.y), fminf(g.z, g.w)));
        tmax = fmaxf(tmax, fmaxf(fmaxf(g.x, g.y), fmaxf(g.z, g.w)));
        tsum += (g.x + g.y) + (g.z + g.w);

        em1 = e0;
        e0 = ep1;
    }

    double dsum = (double)tsum;
    #pragma unroll
    for (int o2 = 32; o2 > 0; o2 >>= 1) {
        tmin = fminf(tmin, __shfl_down(tmin, o2));
        tmax = fmaxf(tmax, __shfl_down(tmax, o2));
        dsum += __shfl_down(dsum, o2);
    }

    if (lane == 0) {
        const int idx = img * WPI + blk * 2 + w;
        pmm[idx] = make_float2(tmin, tmax);
        psum[idx] = dsum;
    }
}

// ---------------------------------------------------------------------------
// kfin1 / kfin2: unchanged from round 12.
// ---------------------------------------------------------------------------
__global__ __launch_bounds__(64) void kfin1(const float2* __restrict__ pmm,
                                            const double* __restrict__ psum,
                                            double* __restrict__ perImg) {
    const int img = blockIdx.x;
    const int lane = threadIdx.x;
    double tot = 0.0;
    for (int k = 0; k < STEPS; ++k) {
        const int o = (k * IMGS + img) * WPI;
        float2 a = pmm[o + lane];
        double s = psum[o + lane];
        float tmn = a.x;
        float tmx = a.y;
        #pragma unroll
        for (int o2 = 32; o2 > 0; o2 >>= 1) {
            tmn = fminf(tmn, __shfl_xor(tmn, o2));
            tmx = fmaxf(tmx, __shfl_xor(tmx, o2));
            s += __shfl_xor(s, o2);
        }
        float ptp = tmx - tmn;
        double sn = (ptp > 0.0f)
                        ? (s - (double)NPIX * (double)tmn) / (double)ptp
                        : s;
        tot += sn * (double)((k + 1) * (k + 1));
    }
    if (lane == 0) perImg[img] = tot;
}

__global__ void kfin2(const double* __restrict__ perImg,
                      float* __restrict__ out) {
    double v = perImg[threadIdx.x];
    #pragma unroll
    for (int o2 = 32; o2 > 0; o2 >>= 1) v += __shfl_down(v, o2);
    if (threadIdx.x == 0)
        out[0] = (float)(v / ((double)IMGS * (double)NPIX));
}

// ---------------------------------------------------------------------------
extern "C" void kernel_launch(void* const* d_in, const int* in_sizes, int n_in,
                              void* d_out, int out_size, void* d_ws, size_t ws_size,
                              hipStream_t stream) {
    const float* x = (const float*)d_in[0];
    const float* y = (const float*)d_in[1];
    float* out = (float*)d_out;

    char* ws = (char*)d_ws;
    const size_t bufBytes = (size_t)IMGS * NPIX * sizeof(float);  // 64 MiB
    float* bufA = (float*)ws;
    float* bufB = (float*)(ws + bufBytes);
    char* p = ws + 2 * bufBytes;
    float2* pmm = (float2*)p;        p += (size_t)STEPS * IMGS * WPI * sizeof(float2);
    double* psum = (double*)p;       p += (size_t)STEPS * IMGS * WPI * sizeof(double);
    double* perImg = (double*)p;

    const size_t SLOT = (size_t)IMGS * WPI;

    // step 0: reads x,y; writes f0; stats s0
    kconv<1, 1><<<NBLK, 128, 0, stream>>>(x, y, nullptr, bufA, nullptr,
                                          pmm, psum);
    float* cur = bufA;
    float* nxt = bufB;
    // pairs (1,2), (3,4), (5,6), (7,8): A = stats-only, B = fused 2-step
    for (int pr = 0; pr < 4; ++pr) {
        const int k = 2 * pr + 1;
        kconv<0, 0><<<NBLK, 128, 0, stream>>>(
            nullptr, nullptr, cur, nullptr,
            pmm + (size_t)(k - 1) * SLOT,
            pmm + (size_t)k * SLOT,
            psum + (size_t)k * SLOT);
        kfuse<<<NBLK, 128, 0, stream>>>(
            cur, nxt,
            pmm + (size_t)(k - 1) * SLOT,
            pmm + (size_t)k * SLOT,
            pmm + (size_t)(k + 1) * SLOT,
            psum + (size_t)(k + 1) * SLOT);
        float* tmp = cur; cur = nxt; nxt = tmp;
    }
    // step 9: stats only from f8
    kconv<0, 0><<<NBLK, 128, 0, stream>>>(
        nullptr, nullptr, cur, nullptr,
        pmm + (size_t)8 * SLOT,
        pmm + (size_t)9 * SLOT,
        psum + (size_t)9 * SLOT);

    kfin1<<<IMGS, 64, 0, stream>>>(pmm, psum, perImg);
    kfin2<<<1, 64, 0, stream>>>(perImg, out);
}